// Round 1
// baseline (660.760 us; speedup 1.0000x reference)
//
#include <hip/hip_runtime.h>
#include <math.h>

typedef __attribute__((ext_vector_type(8))) short bf16x8;
typedef __attribute__((ext_vector_type(4))) float f32x4;
typedef __attribute__((ext_vector_type(4))) unsigned short u16x4;

#define NB 64
#define NS 4096
#define NH 512
#define NE 1024

__device__ __forceinline__ unsigned short f2bf(float f) {
  unsigned int u = __float_as_uint(f);
  u += 0x7fffu + ((u >> 16) & 1u);
  return (unsigned short)(u >> 16);
}

__device__ __forceinline__ void gload_lds16(const void* g, void* l) {
  // async global->LDS, 16B per lane; LDS dest is wave-uniform base + lane*16
  __builtin_amdgcn_global_load_lds((const unsigned int*)g, (unsigned int*)l, 16, 0, 0);
}

// ---- prep: W_h_w f32 -> bf16, same [h][e] row-major layout ----
__global__ __launch_bounds__(256) void prep_w_kernel(const float* __restrict__ W,
                                                     unsigned short* __restrict__ Wb) {
  int i = (blockIdx.x * 256 + threadIdx.x) * 4;
  float4 v = *(const float4*)(W + i);
  u16x4 o;
  o.x = f2bf(v.x); o.y = f2bf(v.y); o.z = f2bf(v.z); o.w = f2bf(v.w);
  *(u16x4*)(Wb + i) = o;
}

// ---- prep: dec[b,h] = decoder_output[b,:] . W_s_w[h,:] + W_s_b[h] + W_h_b[h] ----
__global__ __launch_bounds__(512) void prep_dec_kernel(const float* __restrict__ dec,
                                                       const float* __restrict__ Wsw,
                                                       const float* __restrict__ Wsb,
                                                       const float* __restrict__ Whb,
                                                       float* __restrict__ decb) {
  int b = blockIdx.x;
  int h = threadIdx.x;
  const float4* dr = (const float4*)(dec + b * NH);
  const float4* wr = (const float4*)(Wsw + h * NH);
  float sum = Wsb[h] + Whb[h];
#pragma unroll 8
  for (int i = 0; i < NH / 4; ++i) {
    float4 a = dr[i], w = wr[i];
    sum += a.x * w.x + a.y * w.y + a.z * w.z + a.w * w.w;
  }
  decb[b * NH + h] = sum;
}

// ---- main: fused enc-proj GEMM (bf16 MFMA) + bias + tanh + v-dot -> scores ----
__global__ __launch_bounds__(512) void fused_main(const float* __restrict__ enc,
                                                  const unsigned short* __restrict__ Wb,
                                                  const float* __restrict__ decb,
                                                  const float* __restrict__ vw,
                                                  float* __restrict__ scores) {
  __shared__ unsigned short As[2][64 * 64];    // [m][k], XOR-swizzled, 2x8KB
  __shared__ unsigned short Bs[2][512 * 64];   // [n][k], XOR-swizzled, 2x64KB
  __shared__ float ssc[64];

  const int tid = threadIdx.x;
  const int lane = tid & 63;
  const int wave = tid >> 6;
  const int blk = blockIdx.x;
  const long long m0 = (long long)blk * 64;

  if (tid < 64) ssc[tid] = 0.0f;

  // A staging: thread t loads 8 f32 of row (t>>3), k-granule (t&7); swizzled write
  const int arow = tid >> 3;
  const int agk = tid & 7;
  const float* aload = enc + (m0 + arow) * NE + agk * 8;
  const int awr = arow * 128 + ((agk ^ (arow & 7)) << 4);

  // B staging: per issue (wave*8+j) HW writes 1024B linear; pre-swizzle the
  // global source so swizzled data lands at linear dest (G21 both-sides rule)
  const char* wbB = (const char*)Wb + (lane >> 3) * 2048 +
                    (((lane & 7) ^ ((lane >> 3) & 7)) << 4) + wave * 131072;
  const int bwr = wave * 8192;

  f32x4 acc[4][4];
#pragma unroll
  for (int mi = 0; mi < 4; ++mi)
#pragma unroll
    for (int ni = 0; ni < 4; ++ni) {
      f32x4 z = {0.f, 0.f, 0.f, 0.f};
      acc[mi][ni] = z;
    }

  // prologue: stage kb=0 into buffer 0
  {
    char* bsN = (char*)(&Bs[0][0]) + bwr;
#pragma unroll
    for (int j = 0; j < 8; ++j) gload_lds16(wbB + j * 16384, bsN + j * 1024);
    float4 a0 = *(const float4*)(aload);
    float4 a1 = *(const float4*)(aload + 4);
    union { bf16x8 v; unsigned short u[8]; } p;
    p.u[0] = f2bf(a0.x); p.u[1] = f2bf(a0.y); p.u[2] = f2bf(a0.z); p.u[3] = f2bf(a0.w);
    p.u[4] = f2bf(a1.x); p.u[5] = f2bf(a1.y); p.u[6] = f2bf(a1.z); p.u[7] = f2bf(a1.w);
    *(bf16x8*)((char*)(&As[0][0]) + awr) = p.v;
  }
  __syncthreads();

  const int r15 = lane & 15;
  const int c4 = lane >> 4;
  const int gsw = r15 & 7;

#pragma unroll 2
  for (int kb = 0; kb < 16; ++kb) {
    const int cur = kb & 1;
    const char* Acur = (const char*)(&As[cur][0]);
    const char* Bcur = (const char*)(&Bs[cur][0]);
    float4 a0, a1;
    if (kb < 15) {  // prefetch next tile BEFORE compute so loads fly under MFMA
      char* bsN = (char*)(&Bs[cur ^ 1][0]) + bwr;
      const char* gB = wbB + (kb + 1) * 128;
#pragma unroll
      for (int j = 0; j < 8; ++j) gload_lds16(gB + j * 16384, bsN + j * 1024);
      const float* ap = aload + (kb + 1) * 64;
      a0 = *(const float4*)(ap);
      a1 = *(const float4*)(ap + 4);
    }
#pragma unroll
    for (int kk = 0; kk < 2; ++kk) {
      const int gb = ((((kk << 2) | c4) ^ gsw) << 4);
      bf16x8 af[4], bfr[4];
#pragma unroll
      for (int mi = 0; mi < 4; ++mi)
        af[mi] = *(const bf16x8*)(Acur + (mi * 16 + r15) * 128 + gb);
#pragma unroll
      for (int ni = 0; ni < 4; ++ni)
        bfr[ni] = *(const bf16x8*)(Bcur + ((wave << 6) + ni * 16 + r15) * 128 + gb);
#pragma unroll
      for (int mi = 0; mi < 4; ++mi)
#pragma unroll
        for (int ni = 0; ni < 4; ++ni)
          acc[mi][ni] = __builtin_amdgcn_mfma_f32_16x16x32_bf16(af[mi], bfr[ni],
                                                                acc[mi][ni], 0, 0, 0);
    }
    if (kb < 15) {  // A convert+write after compute (cheap; loads already landed)
      union { bf16x8 v; unsigned short u[8]; } p;
      p.u[0] = f2bf(a0.x); p.u[1] = f2bf(a0.y); p.u[2] = f2bf(a0.z); p.u[3] = f2bf(a0.w);
      p.u[4] = f2bf(a1.x); p.u[5] = f2bf(a1.y); p.u[6] = f2bf(a1.z); p.u[7] = f2bf(a1.w);
      *(bf16x8*)((char*)(&As[cur ^ 1][0]) + awr) = p.v;
    }
    __syncthreads();
  }

  // epilogue: x = tanh(acc + dec[b,h]); score_m += v[h]*x ; C/D layout:
  // col = lane&15 (n), row = (lane>>4)*4 + j (m)
  const int bidx = blk >> 6;
  const float* decrow = decb + bidx * NH;
  float part[4][4];
#pragma unroll
  for (int mi = 0; mi < 4; ++mi)
#pragma unroll
    for (int j = 0; j < 4; ++j) part[mi][j] = 0.f;

#pragma unroll
  for (int ni = 0; ni < 4; ++ni) {
    int col = (wave << 6) + ni * 16 + r15;
    float vc = vw[col];
    float dc = decrow[col];
#pragma unroll
    for (int mi = 0; mi < 4; ++mi)
#pragma unroll
      for (int j = 0; j < 4; ++j)
        part[mi][j] += vc * tanhf(acc[mi][ni][j] + dc);
  }
#pragma unroll
  for (int off = 1; off < 16; off <<= 1)
#pragma unroll
    for (int mi = 0; mi < 4; ++mi)
#pragma unroll
      for (int j = 0; j < 4; ++j)
        part[mi][j] += __shfl_xor(part[mi][j], off, 64);

  if (r15 == 0) {
#pragma unroll
    for (int mi = 0; mi < 4; ++mi)
#pragma unroll
      for (int j = 0; j < 4; ++j)
        atomicAdd(&ssc[mi * 16 + c4 * 4 + j], part[mi][j]);
  }
  __syncthreads();
  if (tid < 64) scores[m0 + tid] = ssc[tid];
}

// ---- masked softmax over S per batch row ----
__global__ __launch_bounds__(1024) void softmax_kernel(const float* __restrict__ scores,
                                                       const int* __restrict__ mask,
                                                       float* __restrict__ out) {
  __shared__ float rmax[16];
  __shared__ float rsum[16];
  const int b = blockIdx.x;
  const int t = threadIdx.x;
  const int wid = t >> 6;
  const int ln = t & 63;
  const int base = b * NS;

  float s[4];
  int mk[4];
  float mx = -INFINITY;
#pragma unroll
  for (int i = 0; i < 4; ++i) {
    int idx = t + i * 1024;
    s[i] = scores[base + idx];
    mk[i] = mask[base + idx];
    if (mk[i]) mx = fmaxf(mx, s[i]);
  }
#pragma unroll
  for (int off = 1; off < 64; off <<= 1) mx = fmaxf(mx, __shfl_xor(mx, off, 64));
  if (ln == 0) rmax[wid] = mx;
  __syncthreads();
  float m2 = -INFINITY;
#pragma unroll
  for (int i = 0; i < 16; ++i) m2 = fmaxf(m2, rmax[i]);

  float e[4];
  float sum = 0.f;
#pragma unroll
  for (int i = 0; i < 4; ++i) {
    e[i] = mk[i] ? expf(s[i] - m2) : 0.f;
    sum += e[i];
  }
#pragma unroll
  for (int off = 1; off < 64; off <<= 1) sum += __shfl_xor(sum, off, 64);
  if (ln == 0) rsum[wid] = sum;
  __syncthreads();
  float tot = 0.f;
#pragma unroll
  for (int i = 0; i < 16; ++i) tot += rsum[i];
  float inv = 1.0f / tot;
#pragma unroll
  for (int i = 0; i < 4; ++i) {
    int idx = t + i * 1024;
    out[base + idx] = e[i] * inv;
  }
}

extern "C" void kernel_launch(void* const* d_in, const int* in_sizes, int n_in,
                              void* d_out, int out_size, void* d_ws, size_t ws_size,
                              hipStream_t stream) {
  const float* dec = (const float*)d_in[0];   // [64,512]
  const float* enc = (const float*)d_in[1];   // [64,4096,1024]
  const int* mask = (const int*)d_in[2];      // [64,4096]
  const float* Whw = (const float*)d_in[3];   // [512,1024]
  const float* Whb = (const float*)d_in[4];   // [512]
  const float* Wsw = (const float*)d_in[5];   // [512,512]
  const float* Wsb = (const float*)d_in[6];   // [512]
  const float* vw = (const float*)d_in[7];    // [1,512]
  float* out = (float*)d_out;                 // [64,4096]

  unsigned short* Wb = (unsigned short*)d_ws;                         // 1 MB
  float* decb = (float*)((char*)d_ws + (1 << 20));                    // 128 KB
  float* scoresb = (float*)((char*)d_ws + (1 << 20) + (128 << 10));   // 1 MB

  prep_w_kernel<<<dim3(512), dim3(256), 0, stream>>>(Whw, Wb);
  prep_dec_kernel<<<dim3(64), dim3(512), 0, stream>>>(dec, Wsw, Wsb, Whb, decb);
  fused_main<<<dim3(4096), dim3(512), 0, stream>>>(enc, Wb, decb, vw, scoresb);
  softmax_kernel<<<dim3(64), dim3(1024), 0, stream>>>(scoresb, mask, out);
}

// Round 2
// 491.947 us; speedup vs baseline: 1.3432x; 1.3432x over previous
//
#include <hip/hip_runtime.h>
#include <math.h>

typedef __attribute__((ext_vector_type(8))) short bf16x8;
typedef __attribute__((ext_vector_type(4))) float f32x4;
typedef __attribute__((ext_vector_type(4))) unsigned short u16x4;

#define NB 64
#define NS 4096
#define NH 512
#define NE 1024
#define APITCH 80  // 64B of bf16 K-data + 16B pad: quarter-wave conflict-free b128 reads

__device__ __forceinline__ unsigned short f2bf(float f) {
  unsigned int u = __float_as_uint(f);
  u += 0x7fffu + ((u >> 16) & 1u);
  return (unsigned short)(u >> 16);
}

// ---- pack W (f32 [512][1024]) into MFMA B-fragment order, bf16 ----
// chunk c = ((w*32 + kb)*4 + ni); lane l's 16B = W[w*64+ni*16+(l&15)][kb*32+(l>>4)*8 .. +7]
// main kernel then does ONE fully-coalesced dwordx4 wave-load per (kb, ni) from L2.
__global__ __launch_bounds__(256) void prep_b_kernel(const float* __restrict__ W,
                                                     unsigned short* __restrict__ Bp) {
  const int t = blockIdx.x * 256 + threadIdx.x;  // 0..65535
  const int lane = t & 63;
  const int ni = (t >> 6) & 3;
  const int kb = (t >> 8) & 31;
  const int w = t >> 13;
  const int col = w * 64 + ni * 16 + (lane & 15);
  const int k0 = kb * 32 + (lane >> 4) * 8;
  const float* src = W + col * NE + k0;
  float4 a = *(const float4*)src;
  float4 b = *(const float4*)(src + 4);
  union { bf16x8 v; unsigned short u[8]; } p;
  p.u[0] = f2bf(a.x); p.u[1] = f2bf(a.y); p.u[2] = f2bf(a.z); p.u[3] = f2bf(a.w);
  p.u[4] = f2bf(b.x); p.u[5] = f2bf(b.y); p.u[6] = f2bf(b.z); p.u[7] = f2bf(b.w);
  *(bf16x8*)(Bp + (long long)t * 8) = p.v;
}

// ---- prep: dec[b,h] = decoder_output[b,:] . W_s_w[h,:] + W_s_b[h] + W_h_b[h] ----
__global__ __launch_bounds__(512) void prep_dec_kernel(const float* __restrict__ dec,
                                                       const float* __restrict__ Wsw,
                                                       const float* __restrict__ Wsb,
                                                       const float* __restrict__ Whb,
                                                       float* __restrict__ decb) {
  int b = blockIdx.x;
  int h = threadIdx.x;
  const float4* dr = (const float4*)(dec + b * NH);
  const float4* wr = (const float4*)(Wsw + h * NH);
  float sum = Wsb[h] + Whb[h];
#pragma unroll 8
  for (int i = 0; i < NH / 4; ++i) {
    float4 a = dr[i], w = wr[i];
    sum += a.x * w.x + a.y * w.y + a.z * w.z + a.w * w.w;
  }
  decb[b * NH + h] = sum;
}

// ---- main: enc-proj GEMM (bf16 MFMA) + bias + tanh + v-dot -> scores ----
// BM=64, BN=512 (all H; encoder read exactly once), BK=32, 512 thr / 8 waves.
// A: LDS double-buffered (10 KB total), reg-prefetched 2 steps ahead from HBM.
// B: straight to VGPRs from L2 (pre-packed frag order), 1 step ahead.
// Sync: raw s_barrier + lgkmcnt(0) only -> vmem prefetches stay in flight (T4).
__global__ __launch_bounds__(512, 4) void fused_main(const float* __restrict__ enc,
                                                     const unsigned short* __restrict__ Bp,
                                                     const float* __restrict__ decb,
                                                     const float* __restrict__ vw,
                                                     float* __restrict__ scores) {
  __shared__ char As[2][64 * APITCH];  // 2 x 5 KB
  __shared__ float ssc[64];

  const int tid = threadIdx.x;
  const int lane = tid & 63;
  const int wave = tid >> 6;
  const int r15 = lane & 15;
  const int c4 = lane >> 4;
  const long long m0 = (long long)blockIdx.x * 64;

  if (tid < 64) ssc[tid] = 0.0f;

  // A staging: thread -> (row = tid>>3, k-granule = tid&7) loads 4 f32 (coalesced 128B/row)
  const int arow = tid >> 3;
  const int agk = tid & 7;
  const float* aload = enc + (m0 + arow) * NE + agk * 4;
  char* const awr0 = &As[0][0] + arow * APITCH + agk * 8;
  char* const awr1 = &As[1][0] + arow * APITCH + agk * 8;

  // B packed base for this wave: chunk ((wave*32+kb)*4+ni)*512 shorts + lane*8
  const unsigned short* const bb = Bp + (long long)wave * 32 * 2048 + lane * 8;

  f32x4 acc[4][4];
#pragma unroll
  for (int mi = 0; mi < 4; ++mi)
#pragma unroll
    for (int ni = 0; ni < 4; ++ni) {
      f32x4 z = {0.f, 0.f, 0.f, 0.f};
      acc[mi][ni] = z;
    }

  // prologue: A(0) -> LDS buf0; B(0) -> regs; A(1) raw -> regs
  {
    float4 a0 = *(const float4*)(aload);
    u16x4 pw;
    pw.x = f2bf(a0.x); pw.y = f2bf(a0.y); pw.z = f2bf(a0.z); pw.w = f2bf(a0.w);
    *(u16x4*)awr0 = pw;
  }
  bf16x8 bcur[4];
#pragma unroll
  for (int ni = 0; ni < 4; ++ni) bcur[ni] = *(const bf16x8*)(bb + ni * 512);
  float4 acur = *(const float4*)(aload + 32);  // raw A for step 1
  __syncthreads();

#pragma unroll 2
  for (int t = 0; t < 32; ++t) {
    const char* Ac = &As[t & 1][0];
    bf16x8 bnxt[4];
    float4 anxt;
    if (t < 31) {
      // B frags for step t+1 (L2, coalesced 1KB wave-loads) -- issued before MFMAs
      const unsigned short* bp = bb + (t + 1) * 2048;
#pragma unroll
      for (int ni = 0; ni < 4; ++ni) bnxt[ni] = *(const bf16x8*)(bp + ni * 512);
      // A for step t+1: convert raw regs -> LDS (opposite buffer)
      u16x4 pw;
      pw.x = f2bf(acur.x); pw.y = f2bf(acur.y); pw.z = f2bf(acur.z); pw.w = f2bf(acur.w);
      *(u16x4*)((t & 1) ? awr0 : awr1) = pw;
    }
    if (t < 30) anxt = *(const float4*)(aload + (t + 2) * 32);  // raw A, 2 steps ahead (HBM)

    bf16x8 af[4];
#pragma unroll
    for (int mi = 0; mi < 4; ++mi)
      af[mi] = *(const bf16x8*)(Ac + (mi * 16 + r15) * APITCH + c4 * 16);
#pragma unroll
    for (int mi = 0; mi < 4; ++mi)
#pragma unroll
      for (int ni = 0; ni < 4; ++ni)
        acc[mi][ni] = __builtin_amdgcn_mfma_f32_16x16x32_bf16(af[mi], bcur[ni],
                                                              acc[mi][ni], 0, 0, 0);
    // all LDS ops (reads consumed above, write for t+1) must land before waves cross
    asm volatile("s_waitcnt lgkmcnt(0)" ::: "memory");
    __builtin_amdgcn_sched_barrier(0);
    __builtin_amdgcn_s_barrier();
    if (t < 31) {
#pragma unroll
      for (int ni = 0; ni < 4; ++ni) bcur[ni] = bnxt[ni];
      acur = anxt;
    }
  }

  // epilogue: x = tanh(acc + dec[b,h]); score += v[h]*x
  // C/D layout: col = lane&15 (n), row = (lane>>4)*4 + j (m)
  const int bidx = (int)(m0 >> 12);  // blockIdx / 64
  const float* decrow = decb + bidx * NH;
  float part[4][4];
#pragma unroll
  for (int mi = 0; mi < 4; ++mi)
#pragma unroll
    for (int j = 0; j < 4; ++j) part[mi][j] = 0.f;

#pragma unroll
  for (int ni = 0; ni < 4; ++ni) {
    int col = (wave << 6) + ni * 16 + r15;
    float vc = vw[col];
    float dc = decrow[col];
#pragma unroll
    for (int mi = 0; mi < 4; ++mi)
#pragma unroll
      for (int j = 0; j < 4; ++j)
        part[mi][j] += vc * tanhf(acc[mi][ni][j] + dc);
  }
#pragma unroll
  for (int off = 1; off < 16; off <<= 1)
#pragma unroll
    for (int mi = 0; mi < 4; ++mi)
#pragma unroll
      for (int j = 0; j < 4; ++j)
        part[mi][j] += __shfl_xor(part[mi][j], off, 64);

  if (r15 == 0) {
#pragma unroll
    for (int mi = 0; mi < 4; ++mi)
#pragma unroll
      for (int j = 0; j < 4; ++j)
        atomicAdd(&ssc[mi * 16 + c4 * 4 + j], part[mi][j]);
  }
  __syncthreads();
  if (tid < 64) scores[m0 + tid] = ssc[tid];
}

// ---- masked softmax over S per batch row ----
__global__ __launch_bounds__(1024) void softmax_kernel(const float* __restrict__ scores,
                                                       const int* __restrict__ mask,
                                                       float* __restrict__ out) {
  __shared__ float rmax[16];
  __shared__ float rsum[16];
  const int b = blockIdx.x;
  const int t = threadIdx.x;
  const int wid = t >> 6;
  const int ln = t & 63;
  const int base = b * NS;

  float s[4];
  int mk[4];
  float mx = -INFINITY;
#pragma unroll
  for (int i = 0; i < 4; ++i) {
    int idx = t + i * 1024;
    s[i] = scores[base + idx];
    mk[i] = mask[base + idx];
    if (mk[i]) mx = fmaxf(mx, s[i]);
  }
#pragma unroll
  for (int off = 1; off < 64; off <<= 1) mx = fmaxf(mx, __shfl_xor(mx, off, 64));
  if (ln == 0) rmax[wid] = mx;
  __syncthreads();
  float m2 = -INFINITY;
#pragma unroll
  for (int i = 0; i < 16; ++i) m2 = fmaxf(m2, rmax[i]);

  float e[4];
  float sum = 0.f;
#pragma unroll
  for (int i = 0; i < 4; ++i) {
    e[i] = mk[i] ? expf(s[i] - m2) : 0.f;
    sum += e[i];
  }
#pragma unroll
  for (int off = 1; off < 64; off <<= 1) sum += __shfl_xor(sum, off, 64);
  if (ln == 0) rsum[wid] = sum;
  __syncthreads();
  float tot = 0.f;
#pragma unroll
  for (int i = 0; i < 16; ++i) tot += rsum[i];
  float inv = 1.0f / tot;
#pragma unroll
  for (int i = 0; i < 4; ++i) {
    int idx = t + i * 1024;
    out[base + idx] = e[i] * inv;
  }
}

extern "C" void kernel_launch(void* const* d_in, const int* in_sizes, int n_in,
                              void* d_out, int out_size, void* d_ws, size_t ws_size,
                              hipStream_t stream) {
  const float* dec = (const float*)d_in[0];   // [64,512]
  const float* enc = (const float*)d_in[1];   // [64,4096,1024]
  const int* mask = (const int*)d_in[2];      // [64,4096]
  const float* Whw = (const float*)d_in[3];   // [512,1024]
  const float* Whb = (const float*)d_in[4];   // [512]
  const float* Wsw = (const float*)d_in[5];   // [512,512]
  const float* Wsb = (const float*)d_in[6];   // [512]
  const float* vw = (const float*)d_in[7];    // [1,512]
  float* out = (float*)d_out;                 // [64,4096]

  unsigned short* Bp = (unsigned short*)d_ws;                         // 1 MB packed W
  float* decb = (float*)((char*)d_ws + (1 << 20));                    // 128 KB
  float* scoresb = (float*)((char*)d_ws + (1 << 20) + (128 << 10));   // 1 MB

  prep_b_kernel<<<dim3(256), dim3(256), 0, stream>>>(Whw, Bp);
  prep_dec_kernel<<<dim3(64), dim3(512), 0, stream>>>(dec, Wsw, Wsb, Whb, decb);
  fused_main<<<dim3(4096), dim3(512), 0, stream>>>(enc, Bp, decb, vw, scoresb);
  softmax_kernel<<<dim3(64), dim3(1024), 0, stream>>>(scoresb, mask, out);
}